// Round 1
// baseline (524.976 us; speedup 1.0000x reference)
//
#include <hip/hip_runtime.h>
#include <cstdint>
#include <cstddef>

#define NE 600000
#define NN 100000

typedef __attribute__((ext_vector_type(8)))  __bf16         bf16x8;
typedef __attribute__((ext_vector_type(16))) float          f32x16;
typedef __attribute__((ext_vector_type(8)))  unsigned short u16x8;
typedef __attribute__((ext_vector_type(2)))  float          f32x2;

__device__ inline unsigned short f2bf(float f) {
    unsigned int u = __builtin_bit_cast(unsigned int, f);
    u += 0x7fffu + ((u >> 16) & 1u);   // round-to-nearest-even
    return (unsigned short)(u >> 16);
}

// Pack W (272x128 f32, row-major) into B-fragment layout:
// Wp[((k>>3)*128 + col)*8 + (k&7)] = bf16(W[k][col])
__global__ void pack_w(const float* __restrict__ W, unsigned short* __restrict__ Wp) {
    int t = blockIdx.x * 256 + threadIdx.x;       // 272*128 = 34816 threads
    if (t >= 272 * 128) return;
    int k = t >> 7, col = t & 127;
    Wp[((k >> 3) * 128 + col) * 8 + (k & 7)] = f2bf(W[t]);
}

// Convert x (100000x128 f32) to bf16. 8 elems/thread, 6250 blocks x 256.
__global__ void cvt_x(const float* __restrict__ x, unsigned short* __restrict__ xb) {
    size_t t = (size_t)(blockIdx.x * 256 + threadIdx.x) * 8;
    float4 a = *(const float4*)(x + t);
    float4 b = *(const float4*)(x + t + 4);
    u16x8 o;
    o[0] = f2bf(a.x); o[1] = f2bf(a.y); o[2] = f2bf(a.z); o[3] = f2bf(a.w);
    o[4] = f2bf(b.x); o[5] = f2bf(b.y); o[6] = f2bf(b.z); o[7] = f2bf(b.w);
    *(u16x8*)(xb + t) = o;
}

// ---------------------------------------------------------------------------
// NEW ARCH: decouple.  node_mm computes Y = x@W_i, Z = x@W_j once per node
// (dense coalesced GEMM, 6x less MFMA work than per-edge).  edge_combine then
// does out[e] = Y[src] + Z[dst] + (ea@W_e + b) as a pure high-occupancy
// gather-add (no LDS, no barriers, no MFMA dependency on the gather).
// ---------------------------------------------------------------------------

// Per wave: 32 node rows x 128 cols, dual accumulators (Y and Z share A-frags).
__global__ __launch_bounds__(256, 2) void node_mm(
    const unsigned short* __restrict__ xb,      // NN x 128 bf16
    const unsigned short* __restrict__ Wp,      // packed W fragments
    float* __restrict__ Y,                      // NN x 128 f32
    float* __restrict__ Z)                      // NN x 128 f32
{
    const int lane = threadIdx.x & 63;
    const int wave = threadIdx.x >> 6;
    const int r = lane & 31;
    const int h = lane >> 5;
    const int nb = (blockIdx.x * 4 + wave) * 32;
    if (nb >= NN) return;                       // wave-uniform

    const bf16x8* Wg = (const bf16x8*)Wp;
    f32x16 accY[4], accZ[4];
#pragma unroll
    for (int t = 0; t < 4; ++t)
#pragma unroll
        for (int i = 0; i < 16; ++i) { accY[t][i] = 0.f; accZ[t][i] = 0.f; }

#pragma unroll
    for (int S = 0; S < 8; ++S) {
        const int kb = 2 * S + h;               // k-chunk of 8 for this half-wave
        bf16x8 a = *(const bf16x8*)(xb + (size_t)(nb + r) * 128 + kb * 8);
#pragma unroll
        for (int t = 0; t < 4; ++t) {
            accY[t] = __builtin_amdgcn_mfma_f32_32x32x16_bf16(
                          a, Wg[kb * 128 + t * 32 + r],        accY[t], 0, 0, 0);
            accZ[t] = __builtin_amdgcn_mfma_f32_32x32x16_bf16(
                          a, Wg[(16 + kb) * 128 + t * 32 + r], accZ[t], 0, 0, 0);
        }
    }

#pragma unroll
    for (int t = 0; t < 4; ++t)
#pragma unroll
        for (int i = 0; i < 16; ++i) {
            int row = (i & 3) + 8 * (i >> 2) + 4 * h;
            Y[(size_t)(nb + row) * 128 + t * 32 + r] = accY[t][i];
            Z[(size_t)(nb + row) * 128 + t * 32 + r] = accZ[t][i];
        }
}

// Each wave owns 64 consecutive edges; lane owns cols {2*lane, 2*lane+1}.
// Y/Z row loads are 512B fully-coalesced with SGPR row base (readlane index).
// ea@W_e done in exact f32 VALU: W_e column pair in 32 VGPRs, ea broadcast
// via v_readlane from a coalesced per-4-edge staging register.
__global__ __launch_bounds__(256, 5) void edge_combine(
    const float* __restrict__ Y,                // NN x 128 f32
    const float* __restrict__ Z,                // NN x 128 f32
    const int*   __restrict__ ei,               // 2 x NE
    const float* __restrict__ ea,               // NE x 16
    const float* __restrict__ W,                // 272 x 128 f32 (raw)
    const float* __restrict__ bias,             // 128
    float* __restrict__ out)                    // NE x 128
{
    const int lane = threadIdx.x & 63;
    const int w = (blockIdx.x * 256 + threadIdx.x) >> 6;    // global wave id
    if (w >= NE / 64) return;                   // 9375 waves cover NE exactly
    const int ebase = w * 64;

    // W_e columns for this lane (held in registers for the whole kernel)
    float wex[16], wey[16];
#pragma unroll
    for (int k = 0; k < 16; ++k) {
        f32x2 t = *(const f32x2*)(W + (size_t)(256 + k) * 128 + 2 * lane);
        wex[k] = t.x; wey[k] = t.y;
    }
    const f32x2 bv = *(const f32x2*)(bias + 2 * lane);

    // all 64 src / dst indices of this wave, one per lane
    const int srcv = ei[ebase + lane];
    const int dstv = ei[NE + ebase + lane];
    const float* eab = ea + (size_t)ebase * 16;

#pragma unroll 2
    for (int jo = 0; jo < 16; ++jo) {
        // ea for edges 4*jo .. 4*jo+3 (256B coalesced, streaming)
        float eag = __builtin_nontemporal_load(eab + jo * 64 + lane);
#pragma unroll
        for (int ji = 0; ji < 4; ++ji) {
            const int j = jo * 4 + ji;
            const int s = __builtin_amdgcn_readlane(srcv, j);   // SGPR row base
            const int d = __builtin_amdgcn_readlane(dstv, j);
            f32x2 y = *(const f32x2*)(Y + ((size_t)s << 7) + 2 * lane);
            f32x2 z = *(const f32x2*)(Z + ((size_t)d << 7) + 2 * lane);

            float ax = bv.x, ay = bv.y;
#pragma unroll
            for (int k = 0; k < 16; ++k) {
                int eb = __builtin_amdgcn_readlane(
                             __builtin_bit_cast(int, eag), ji * 16 + k);
                float e = __builtin_bit_cast(float, eb);
                ax = fmaf(e, wex[k], ax);
                ay = fmaf(e, wey[k], ay);
            }
            f32x2 o;
            o.x = ax + y.x + z.x;
            o.y = ay + y.y + z.y;
            __builtin_nontemporal_store(
                o, (f32x2*)(out + ((size_t)(ebase + j) << 7) + 2 * lane));
        }
    }
}

// ---------------------------------------------------------------------------
// Fallback path (previous best kernel) if workspace is too small for Y/Z.
// ---------------------------------------------------------------------------

#define WAIT_VM(n) do { asm volatile("" ::: "memory");                      \
                        __builtin_amdgcn_s_waitcnt(0x0F70 | (n));           \
                        asm volatile("" ::: "memory"); } while (0)

__global__ __launch_bounds__(256, 2) void edge_mm2(
    const unsigned short* __restrict__ xb,
    const unsigned short* __restrict__ Wp,
    const int* __restrict__ ei,
    const float* __restrict__ ea,
    const float* __restrict__ bias,
    float* __restrict__ out)
{
    __shared__ __attribute__((aligned(16))) unsigned short Abuf[4][2][32][128];

    const int lane = threadIdx.x & 63;
    const int wave = threadIdx.x >> 6;
    const int r  = lane & 31;
    const int h  = lane >> 5;
    const int g4 = lane >> 4;
    const int sl = lane & 15;
    const int ebase = blockIdx.x * 128 + wave * 32;
    if (ebase >= NE) return;
    const int e = ebase + r;

#pragma unroll
    for (int i = 0; i < 8; ++i) {
        int row = 4 * i + g4;
        int nidx = ei[ebase + row];
        const unsigned short* gs = xb + (size_t)nidx * 128 + ((sl ^ (row & 15)) << 3);
        __builtin_amdgcn_global_load_lds(
            (const __attribute__((address_space(1))) void*)gs,
            (__attribute__((address_space(3))) void*)&Abuf[wave][0][4 * i][0],
            16, 0, 0);
    }
#pragma unroll
    for (int i = 0; i < 8; ++i) {
        int row = 4 * i + g4;
        int nidx = ei[NE + ebase + row];
        const unsigned short* gs = xb + (size_t)nidx * 128 + ((sl ^ (row & 15)) << 3);
        __builtin_amdgcn_global_load_lds(
            (const __attribute__((address_space(1))) void*)gs,
            (__attribute__((address_space(3))) void*)&Abuf[wave][1][4 * i][0],
            16, 0, 0);
    }

    const float4* ae = (const float4*)(ea + (size_t)e * 16);
    float4 p = ae[2 * h], q = ae[2 * h + 1];

    f32x16 acc[4];
#pragma unroll
    for (int t = 0; t < 4; ++t)
#pragma unroll
        for (int i = 0; i < 16; ++i) acc[t][i] = 0.f;

    const bf16x8* Wg = (const bf16x8*)Wp;
    const int rm = r & 15;

    WAIT_VM(8);
#pragma unroll
    for (int S = 0; S < 8; ++S) {
        int kb = 2 * S + h;
        bf16x8 a = *(const bf16x8*)&Abuf[wave][0][r][(kb ^ rm) << 3];
#pragma unroll
        for (int t = 0; t < 4; ++t) {
            bf16x8 b = Wg[kb * 128 + t * 32 + r];
            acc[t] = __builtin_amdgcn_mfma_f32_32x32x16_bf16(a, b, acc[t], 0, 0, 0);
        }
    }

    WAIT_VM(0);
#pragma unroll
    for (int S = 0; S < 8; ++S) {
        int kb = 2 * S + h;
        bf16x8 a = *(const bf16x8*)&Abuf[wave][1][r][(kb ^ rm) << 3];
#pragma unroll
        for (int t = 0; t < 4; ++t) {
            bf16x8 b = Wg[(16 + kb) * 128 + t * 32 + r];
            acc[t] = __builtin_amdgcn_mfma_f32_32x32x16_bf16(a, b, acc[t], 0, 0, 0);
        }
    }

    {
        u16x8 o;
        o[0] = f2bf(p.x); o[1] = f2bf(p.y); o[2] = f2bf(p.z); o[3] = f2bf(p.w);
        o[4] = f2bf(q.x); o[5] = f2bf(q.y); o[6] = f2bf(q.z); o[7] = f2bf(q.w);
        bf16x8 a = __builtin_bit_cast(bf16x8, o);
#pragma unroll
        for (int t = 0; t < 4; ++t) {
            bf16x8 b = Wg[(32 + h) * 128 + t * 32 + r];
            acc[t] = __builtin_amdgcn_mfma_f32_32x32x16_bf16(a, b, acc[t], 0, 0, 0);
        }
    }

    float* orow = out + (size_t)ebase * 128;
#pragma unroll
    for (int t = 0; t < 4; ++t) {
        float bv = bias[t * 32 + r];
#pragma unroll
        for (int i = 0; i < 16; ++i) {
            int row = (i & 3) + 8 * (i >> 2) + 4 * h;
            orow[(size_t)row * 128 + t * 32 + r] = acc[t][i] + bv;
        }
    }
}

__global__ __launch_bounds__(256, 2) void edge_mm_fb(
    const float* __restrict__ x,
    const unsigned short* __restrict__ Wp,
    const int* __restrict__ ei,
    const float* __restrict__ ea,
    const float* __restrict__ bias,
    float* __restrict__ out)
{
    __shared__ unsigned short Wl[32 * 128 * 8];
    {
        const uint4* Wg = (const uint4*)Wp;
        uint4* Ws = (uint4*)Wl;
#pragma unroll
        for (int i = 0; i < 16; ++i)
            Ws[threadIdx.x + 256 * i] = Wg[threadIdx.x + 256 * i];
    }
    const int lane = threadIdx.x & 63;
    const int wave = threadIdx.x >> 6;
    const int r = lane & 31;
    const int h = lane >> 5;
    const long ebase = (long)blockIdx.x * 128 + wave * 32;
    __syncthreads();
    if (ebase >= NE) return;
    const int e = (int)ebase + r;
    const int src = ei[e];
    const int dst = ei[NE + e];
    f32x16 acc[4];
#pragma unroll
    for (int t = 0; t < 4; ++t)
#pragma unroll
        for (int i = 0; i < 16; ++i) acc[t][i] = 0.f;
    const bf16x8* Wv = (const bf16x8*)Wl;
#pragma unroll
    for (int ph = 0; ph < 2; ++ph) {
        int node = ph ? dst : src;
#pragma unroll
        for (int s = 0; s < 8; ++s) {
            const float4* ax = (const float4*)(x + (size_t)node * 128);
            float4 pp = ax[(2 * s + h) * 2], qq = ax[(2 * s + h) * 2 + 1];
            u16x8 o;
            o[0] = f2bf(pp.x); o[1] = f2bf(pp.y); o[2] = f2bf(pp.z); o[3] = f2bf(pp.w);
            o[4] = f2bf(qq.x); o[5] = f2bf(qq.y); o[6] = f2bf(qq.z); o[7] = f2bf(qq.w);
            bf16x8 a = __builtin_bit_cast(bf16x8, o);
            int S = ph * 8 + s;
#pragma unroll
            for (int t = 0; t < 4; ++t) {
                bf16x8 b = Wv[(2 * S + h) * 128 + t * 32 + r];
                acc[t] = __builtin_amdgcn_mfma_f32_32x32x16_bf16(a, b, acc[t], 0, 0, 0);
            }
        }
    }
    {
        const float4* ae = (const float4*)(ea + (size_t)e * 16);
        float4 pp = ae[2 * h], qq = ae[2 * h + 1];
        u16x8 o;
        o[0] = f2bf(pp.x); o[1] = f2bf(pp.y); o[2] = f2bf(pp.z); o[3] = f2bf(pp.w);
        o[4] = f2bf(qq.x); o[5] = f2bf(qq.y); o[6] = f2bf(qq.z); o[7] = f2bf(qq.w);
        bf16x8 a = __builtin_bit_cast(bf16x8, o);
        const bf16x8* Wg = (const bf16x8*)Wp;
#pragma unroll
        for (int t = 0; t < 4; ++t) {
            bf16x8 b = Wg[(32 + h) * 128 + t * 32 + r];
            acc[t] = __builtin_amdgcn_mfma_f32_32x32x16_bf16(a, b, acc[t], 0, 0, 0);
        }
    }
    float* orow = out + (size_t)ebase * 128;
#pragma unroll
    for (int t = 0; t < 4; ++t) {
        float bv = bias[t * 32 + r];
#pragma unroll
        for (int i = 0; i < 16; ++i) {
            int row = (i & 3) + 8 * (i >> 2) + 4 * h;
            orow[(size_t)row * 128 + t * 32 + r] = acc[t][i] + bv;
        }
    }
}

extern "C" void kernel_launch(void* const* d_in, const int* in_sizes, int n_in,
                              void* d_out, int out_size, void* d_ws, size_t ws_size,
                              hipStream_t stream) {
    const float* x  = (const float*)d_in[0];
    const int*   ei = (const int*)d_in[1];
    const float* ea = (const float*)d_in[2];
    const float* W  = (const float*)d_in[3];
    const float* b  = (const float*)d_in[4];
    float* out = (float*)d_out;

    unsigned short* Wp = (unsigned short*)d_ws;                        // 69,632 B
    unsigned short* xb = (unsigned short*)((char*)d_ws + 69632);       // 25.6 MB
    float* Yb = (float*)((char*)d_ws + 69632 + 25600000);              // 51.2 MB
    float* Zb = (float*)((char*)d_ws + 69632 + 25600000 + 51200000);   // 51.2 MB

    const size_t need_mid  = 69632 + (size_t)NN * 128 * 2;
    const size_t need_full = need_mid + 2ull * NN * 128 * 4;

    hipLaunchKernelGGL(pack_w, dim3(136), dim3(256), 0, stream, W, Wp);

    if (ws_size >= need_full) {
        hipLaunchKernelGGL(cvt_x, dim3(6250), dim3(256), 0, stream, x, xb);
        hipLaunchKernelGGL(node_mm, dim3(782), dim3(256), 0, stream, xb, Wp, Yb, Zb);
        hipLaunchKernelGGL(edge_combine, dim3(2344), dim3(256), 0, stream,
                           Yb, Zb, ei, ea, W, b, out);
    } else if (ws_size >= need_mid) {
        hipLaunchKernelGGL(cvt_x, dim3(6250), dim3(256), 0, stream, x, xb);
        hipLaunchKernelGGL(edge_mm2, dim3(4688), dim3(256), 0, stream,
                           xb, Wp, ei, ea, b, out);
    } else {
        hipLaunchKernelGGL(edge_mm_fb, dim3(4688), dim3(256), 0, stream,
                           x, Wp, ei, ea, b, out);
    }
}

// Round 2
// 503.672 us; speedup vs baseline: 1.0423x; 1.0423x over previous
//
#include <hip/hip_runtime.h>
#include <cstdint>
#include <cstddef>

#define NE 600000
#define NN 100000

typedef __attribute__((ext_vector_type(8)))  __bf16         bf16x8;
typedef __attribute__((ext_vector_type(16))) float          f32x16;
typedef __attribute__((ext_vector_type(8)))  unsigned short u16x8;
typedef __attribute__((ext_vector_type(2)))  float          f32x2;

__device__ inline unsigned short f2bf(float f) {
    unsigned int u = __builtin_bit_cast(unsigned int, f);
    u += 0x7fffu + ((u >> 16) & 1u);   // round-to-nearest-even
    return (unsigned short)(u >> 16);
}

// Pack W (272x128 f32, row-major) into B-fragment layout:
// Wp[((k>>3)*128 + col)*8 + (k&7)] = bf16(W[k][col])
__global__ void pack_w(const float* __restrict__ W, unsigned short* __restrict__ Wp) {
    int t = blockIdx.x * 256 + threadIdx.x;       // 272*128 = 34816 threads
    if (t >= 272 * 128) return;
    int k = t >> 7, col = t & 127;
    Wp[((k >> 3) * 128 + col) * 8 + (k & 7)] = f2bf(W[t]);
}

// Convert x (100000x128 f32) to bf16 (fallback path only).
__global__ void cvt_x(const float* __restrict__ x, unsigned short* __restrict__ xb) {
    size_t t = (size_t)(blockIdx.x * 256 + threadIdx.x) * 8;
    float4 a = *(const float4*)(x + t);
    float4 b = *(const float4*)(x + t + 4);
    u16x8 o;
    o[0] = f2bf(a.x); o[1] = f2bf(a.y); o[2] = f2bf(a.z); o[3] = f2bf(a.w);
    o[4] = f2bf(b.x); o[5] = f2bf(b.y); o[6] = f2bf(b.z); o[7] = f2bf(b.w);
    *(u16x8*)(xb + t) = o;
}

// ---------------------------------------------------------------------------
// Decoupled arch v2.
// node_mm: Y = x@W_i, Z = x@W_j once per node (reads f32 x directly,
//          converts in-register; no cvt_x pass needed).
// edge_combine: out[e] = Y[src] + Z[dst] + (ea@W_e + b), pure gather-add
//          with all loop-invariant data (W_e cols, bias, 64 edge indices,
//          all 64x16 ea values) hoisted into registers BEFORE the loop, and
//          an 8-deep static software pipeline on the Y/Z row gathers.
// ---------------------------------------------------------------------------

__global__ __launch_bounds__(256, 2) void node_mm(
    const float* __restrict__ x,                // NN x 128 f32
    const unsigned short* __restrict__ Wp,      // packed W fragments
    float* __restrict__ Y,                      // NN x 128 f32
    float* __restrict__ Z)                      // NN x 128 f32
{
    const int lane = threadIdx.x & 63;
    const int wave = threadIdx.x >> 6;
    const int r = lane & 31;
    const int h = lane >> 5;
    const int nb = (blockIdx.x * 4 + wave) * 32;
    if (nb >= NN) return;                       // wave-uniform

    const bf16x8* Wg = (const bf16x8*)Wp;
    f32x16 accY[4], accZ[4];
#pragma unroll
    for (int t = 0; t < 4; ++t)
#pragma unroll
        for (int i = 0; i < 16; ++i) { accY[t][i] = 0.f; accZ[t][i] = 0.f; }

    const float4* ax4 = (const float4*)(x + (size_t)(nb + r) * 128);
#pragma unroll
    for (int S = 0; S < 8; ++S) {
        const int kb = 2 * S + h;               // k-chunk of 8 for this half-wave
        float4 pp = ax4[kb * 2], qq = ax4[kb * 2 + 1];
        u16x8 o;
        o[0] = f2bf(pp.x); o[1] = f2bf(pp.y); o[2] = f2bf(pp.z); o[3] = f2bf(pp.w);
        o[4] = f2bf(qq.x); o[5] = f2bf(qq.y); o[6] = f2bf(qq.z); o[7] = f2bf(qq.w);
        bf16x8 a = __builtin_bit_cast(bf16x8, o);
#pragma unroll
        for (int t = 0; t < 4; ++t) {
            accY[t] = __builtin_amdgcn_mfma_f32_32x32x16_bf16(
                          a, Wg[kb * 128 + t * 32 + r],        accY[t], 0, 0, 0);
            accZ[t] = __builtin_amdgcn_mfma_f32_32x32x16_bf16(
                          a, Wg[(16 + kb) * 128 + t * 32 + r], accZ[t], 0, 0, 0);
        }
    }

#pragma unroll
    for (int t = 0; t < 4; ++t)
#pragma unroll
        for (int i = 0; i < 16; ++i) {
            int row = (i & 3) + 8 * (i >> 2) + 4 * h;
            Y[(size_t)(nb + row) * 128 + t * 32 + r] = accY[t][i];
            Z[(size_t)(nb + row) * 128 + t * 32 + r] = accZ[t][i];
        }
}

// Wave owns 64 consecutive edges; lane owns output cols {2*lane, 2*lane+1}.
// ea[j][k] for edge j of the wave lives in VGPR raw[j>>2], lane (j&3)*16+k
// (readlane from REGISTERS, zero memory deps in the loop).
__global__ __launch_bounds__(256, 4) void edge_combine(
    const float* __restrict__ Y,                // NN x 128 f32
    const float* __restrict__ Z,                // NN x 128 f32
    const int*   __restrict__ ei,               // 2 x NE
    const float* __restrict__ ea,               // NE x 16
    const float* __restrict__ W,                // 272 x 128 f32 (raw)
    const float* __restrict__ bias,             // 128
    float* __restrict__ out)                    // NE x 128
{
    const int lane = threadIdx.x & 63;
    const int w = (blockIdx.x * 256 + threadIdx.x) >> 6;    // global wave id
    if (w >= NE / 64) return;                   // 9375 waves cover NE exactly
    const int ebase = w * 64;

    // ---- loop-invariant register state (all loads happen HERE) ----
    f32x2 we[16];                               // W_e column pair
#pragma unroll
    for (int k = 0; k < 16; ++k)
        we[k] = *(const f32x2*)(W + (size_t)(256 + k) * 128 + 2 * lane);
    const f32x2 bv = *(const f32x2*)(bias + 2 * lane);

    const int srcv = ei[ebase + lane];          // 64 src indices, one per lane
    const int dstv = ei[NE + ebase + lane];     // 64 dst indices

    int raw[16];                                // all 64x16 ea values of the wave
#pragma unroll
    for (int m = 0; m < 16; ++m)
        raw[m] = __builtin_bit_cast(int,
                     ea[(size_t)ebase * 16 + m * 64 + lane]);

    // ---- 8-deep software-pipelined gather loop (fully static indices) ----
    f32x2 yv[8], zv[8];
#pragma unroll
    for (int i = 0; i < 8; ++i) {
        int s = __builtin_amdgcn_readlane(srcv, i);
        int d = __builtin_amdgcn_readlane(dstv, i);
        yv[i] = *(const f32x2*)(Y + ((size_t)s << 7) + 2 * lane);
        zv[i] = *(const f32x2*)(Z + ((size_t)d << 7) + 2 * lane);
    }

#pragma unroll
    for (int j = 0; j < 64; ++j) {
        const int slot = j & 7;
        f32x2 y = yv[slot], z = zv[slot];
        if (j + 8 < 64) {                       // compile-time guard after unroll
            int s = __builtin_amdgcn_readlane(srcv, j + 8);
            int d = __builtin_amdgcn_readlane(dstv, j + 8);
            yv[slot] = *(const f32x2*)(Y + ((size_t)s << 7) + 2 * lane);
            zv[slot] = *(const f32x2*)(Z + ((size_t)d << 7) + 2 * lane);
        }
        // E = ea[j] @ W_e + b  (exact f32, v_pk_fma via f32x2)
        f32x2 acc = bv;
#pragma unroll
        for (int k = 0; k < 16; ++k) {
            float e = __builtin_bit_cast(float,
                          __builtin_amdgcn_readlane(raw[j >> 2], (j & 3) * 16 + k));
            acc = acc + we[k] * e;
        }
        f32x2 o = acc + y + z;
        __builtin_nontemporal_store(
            o, (f32x2*)(out + ((size_t)(ebase + j) << 7) + 2 * lane));
    }
}

// ---------------------------------------------------------------------------
// Fallback path (previous verified kernels) if workspace is too small.
// ---------------------------------------------------------------------------

#define WAIT_VM(n) do { asm volatile("" ::: "memory");                      \
                        __builtin_amdgcn_s_waitcnt(0x0F70 | (n));           \
                        asm volatile("" ::: "memory"); } while (0)

__global__ __launch_bounds__(256, 2) void edge_mm2(
    const unsigned short* __restrict__ xb,
    const unsigned short* __restrict__ Wp,
    const int* __restrict__ ei,
    const float* __restrict__ ea,
    const float* __restrict__ bias,
    float* __restrict__ out)
{
    __shared__ __attribute__((aligned(16))) unsigned short Abuf[4][2][32][128];

    const int lane = threadIdx.x & 63;
    const int wave = threadIdx.x >> 6;
    const int r  = lane & 31;
    const int h  = lane >> 5;
    const int g4 = lane >> 4;
    const int sl = lane & 15;
    const int ebase = blockIdx.x * 128 + wave * 32;
    if (ebase >= NE) return;
    const int e = ebase + r;

#pragma unroll
    for (int i = 0; i < 8; ++i) {
        int row = 4 * i + g4;
        int nidx = ei[ebase + row];
        const unsigned short* gs = xb + (size_t)nidx * 128 + ((sl ^ (row & 15)) << 3);
        __builtin_amdgcn_global_load_lds(
            (const __attribute__((address_space(1))) void*)gs,
            (__attribute__((address_space(3))) void*)&Abuf[wave][0][4 * i][0],
            16, 0, 0);
    }
#pragma unroll
    for (int i = 0; i < 8; ++i) {
        int row = 4 * i + g4;
        int nidx = ei[NE + ebase + row];
        const unsigned short* gs = xb + (size_t)nidx * 128 + ((sl ^ (row & 15)) << 3);
        __builtin_amdgcn_global_load_lds(
            (const __attribute__((address_space(1))) void*)gs,
            (__attribute__((address_space(3))) void*)&Abuf[wave][1][4 * i][0],
            16, 0, 0);
    }

    const float4* ae = (const float4*)(ea + (size_t)e * 16);
    float4 p = ae[2 * h], q = ae[2 * h + 1];

    f32x16 acc[4];
#pragma unroll
    for (int t = 0; t < 4; ++t)
#pragma unroll
        for (int i = 0; i < 16; ++i) acc[t][i] = 0.f;

    const bf16x8* Wg = (const bf16x8*)Wp;
    const int rm = r & 15;

    WAIT_VM(8);
#pragma unroll
    for (int S = 0; S < 8; ++S) {
        int kb = 2 * S + h;
        bf16x8 a = *(const bf16x8*)&Abuf[wave][0][r][(kb ^ rm) << 3];
#pragma unroll
        for (int t = 0; t < 4; ++t) {
            bf16x8 b = Wg[kb * 128 + t * 32 + r];
            acc[t] = __builtin_amdgcn_mfma_f32_32x32x16_bf16(a, b, acc[t], 0, 0, 0);
        }
    }

    WAIT_VM(0);
#pragma unroll
    for (int S = 0; S < 8; ++S) {
        int kb = 2 * S + h;
        bf16x8 a = *(const bf16x8*)&Abuf[wave][1][r][(kb ^ rm) << 3];
#pragma unroll
        for (int t = 0; t < 4; ++t) {
            bf16x8 b = Wg[(16 + kb) * 128 + t * 32 + r];
            acc[t] = __builtin_amdgcn_mfma_f32_32x32x16_bf16(a, b, acc[t], 0, 0, 0);
        }
    }

    {
        u16x8 o;
        o[0] = f2bf(p.x); o[1] = f2bf(p.y); o[2] = f2bf(p.z); o[3] = f2bf(p.w);
        o[4] = f2bf(q.x); o[5] = f2bf(q.y); o[6] = f2bf(q.z); o[7] = f2bf(q.w);
        bf16x8 a = __builtin_bit_cast(bf16x8, o);
#pragma unroll
        for (int t = 0; t < 4; ++t) {
            bf16x8 b = Wg[(32 + h) * 128 + t * 32 + r];
            acc[t] = __builtin_amdgcn_mfma_f32_32x32x16_bf16(a, b, acc[t], 0, 0, 0);
        }
    }

    float* orow = out + (size_t)ebase * 128;
#pragma unroll
    for (int t = 0; t < 4; ++t) {
        float bv = bias[t * 32 + r];
#pragma unroll
        for (int i = 0; i < 16; ++i) {
            int row = (i & 3) + 8 * (i >> 2) + 4 * h;
            orow[(size_t)row * 128 + t * 32 + r] = acc[t][i] + bv;
        }
    }
}

__global__ __launch_bounds__(256, 2) void edge_mm_fb(
    const float* __restrict__ x,
    const unsigned short* __restrict__ Wp,
    const int* __restrict__ ei,
    const float* __restrict__ ea,
    const float* __restrict__ bias,
    float* __restrict__ out)
{
    __shared__ unsigned short Wl[32 * 128 * 8];
    {
        const uint4* Wg = (const uint4*)Wp;
        uint4* Ws = (uint4*)Wl;
#pragma unroll
        for (int i = 0; i < 16; ++i)
            Ws[threadIdx.x + 256 * i] = Wg[threadIdx.x + 256 * i];
    }
    const int lane = threadIdx.x & 63;
    const int wave = threadIdx.x >> 6;
    const int r = lane & 31;
    const int h = lane >> 5;
    const long ebase = (long)blockIdx.x * 128 + wave * 32;
    __syncthreads();
    if (ebase >= NE) return;
    const int e = (int)ebase + r;
    const int src = ei[e];
    const int dst = ei[NE + e];
    f32x16 acc[4];
#pragma unroll
    for (int t = 0; t < 4; ++t)
#pragma unroll
        for (int i = 0; i < 16; ++i) acc[t][i] = 0.f;
    const bf16x8* Wv = (const bf16x8*)Wl;
#pragma unroll
    for (int ph = 0; ph < 2; ++ph) {
        int node = ph ? dst : src;
#pragma unroll
        for (int s = 0; s < 8; ++s) {
            const float4* ax = (const float4*)(x + (size_t)node * 128);
            float4 pp = ax[(2 * s + h) * 2], qq = ax[(2 * s + h) * 2 + 1];
            u16x8 o;
            o[0] = f2bf(pp.x); o[1] = f2bf(pp.y); o[2] = f2bf(pp.z); o[3] = f2bf(pp.w);
            o[4] = f2bf(qq.x); o[5] = f2bf(qq.y); o[6] = f2bf(qq.z); o[7] = f2bf(qq.w);
            bf16x8 a = __builtin_bit_cast(bf16x8, o);
            int S = ph * 8 + s;
#pragma unroll
            for (int t = 0; t < 4; ++t) {
                bf16x8 b = Wv[(2 * S + h) * 128 + t * 32 + r];
                acc[t] = __builtin_amdgcn_mfma_f32_32x32x16_bf16(a, b, acc[t], 0, 0, 0);
            }
        }
    }
    {
        const float4* ae = (const float4*)(ea + (size_t)e * 16);
        float4 pp = ae[2 * h], qq = ae[2 * h + 1];
        u16x8 o;
        o[0] = f2bf(pp.x); o[1] = f2bf(pp.y); o[2] = f2bf(pp.z); o[3] = f2bf(pp.w);
        o[4] = f2bf(qq.x); o[5] = f2bf(qq.y); o[6] = f2bf(qq.z); o[7] = f2bf(qq.w);
        bf16x8 a = __builtin_bit_cast(bf16x8, o);
        const bf16x8* Wg = (const bf16x8*)Wp;
#pragma unroll
        for (int t = 0; t < 4; ++t) {
            bf16x8 b = Wg[(32 + h) * 128 + t * 32 + r];
            acc[t] = __builtin_amdgcn_mfma_f32_32x32x16_bf16(a, b, acc[t], 0, 0, 0);
        }
    }
    float* orow = out + (size_t)ebase * 128;
#pragma unroll
    for (int t = 0; t < 4; ++t) {
        float bv = bias[t * 32 + r];
#pragma unroll
        for (int i = 0; i < 16; ++i) {
            int row = (i & 3) + 8 * (i >> 2) + 4 * h;
            orow[(size_t)row * 128 + t * 32 + r] = acc[t][i] + bv;
        }
    }
}

extern "C" void kernel_launch(void* const* d_in, const int* in_sizes, int n_in,
                              void* d_out, int out_size, void* d_ws, size_t ws_size,
                              hipStream_t stream) {
    const float* x  = (const float*)d_in[0];
    const int*   ei = (const int*)d_in[1];
    const float* ea = (const float*)d_in[2];
    const float* W  = (const float*)d_in[3];
    const float* b  = (const float*)d_in[4];
    float* out = (float*)d_out;

    unsigned short* Wp = (unsigned short*)d_ws;                        // 69,632 B
    float* Yb = (float*)((char*)d_ws + 69632);                         // 51.2 MB
    float* Zb = (float*)((char*)d_ws + 69632 + 51200000);              // 51.2 MB
    unsigned short* xb = (unsigned short*)((char*)d_ws + 69632);       // (mid path)

    const size_t need_mid  = 69632 + (size_t)NN * 128 * 2;
    const size_t need_full = 69632 + 2ull * NN * 128 * 4;

    hipLaunchKernelGGL(pack_w, dim3(136), dim3(256), 0, stream, W, Wp);

    if (ws_size >= need_full) {
        hipLaunchKernelGGL(node_mm, dim3(782), dim3(256), 0, stream, x, Wp, Yb, Zb);
        hipLaunchKernelGGL(edge_combine, dim3(2344), dim3(256), 0, stream,
                           Yb, Zb, ei, ea, W, b, out);
    } else if (ws_size >= need_mid) {
        hipLaunchKernelGGL(cvt_x, dim3(6250), dim3(256), 0, stream, x, xb);
        hipLaunchKernelGGL(edge_mm2, dim3(4688), dim3(256), 0, stream,
                           xb, Wp, ei, ea, b, out);
    } else {
        hipLaunchKernelGGL(edge_mm_fb, dim3(4688), dim3(256), 0, stream,
                           x, Wp, ei, ea, b, out);
    }
}